// Round 14
// baseline (96.212 us; speedup 1.0000x reference)
//
#include <hip/hip_runtime.h>
#include <hip/hip_bf16.h>
#include <stdint.h>

#define B_  2
#define NF_ 2048
#define NE_ 4096
#define FD_ 128
#define HD_ 64
#define H_  4

#define LOG2E 1.44269504f
#define KH    8.65617025f   // (12 * log2e) / 2

typedef unsigned long long u64;
typedef __attribute__((ext_vector_type(4))) float f32x4;
typedef __attribute__((ext_vector_type(8))) short bf16x8;
typedef __attribute__((ext_vector_type(4))) unsigned uint32x4;

__device__ __forceinline__ float wave_sum64(float v) {
  #pragma unroll
  for (int m = 32; m >= 1; m >>= 1) v += __shfl_xor(v, m, 64);
  return v;
}
__device__ __forceinline__ float wave_max64(float v) {
  #pragma unroll
  for (int m = 32; m >= 1; m >>= 1) v = fmaxf(v, __shfl_xor(v, m, 64));
  return v;
}
__device__ __forceinline__ unsigned short bf16rne(float x) {
  unsigned u = __float_as_uint(x);
  return (unsigned short)((u + 0x7FFFu + ((u >> 16) & 1u)) >> 16);
}

// ---- pre: tile W into A-fragment bf16 layout + Wa = (W @ a) * log2e ----
__global__ __launch_bounds__(256) void pre_kernel(
    const float* __restrict__ Wf, const float* __restrict__ We,
    const float* __restrict__ a_fe, const float* __restrict__ a_ef,
    __hip_bfloat16* __restrict__ Wfrag, float* __restrict__ Wa)
{
  const int lane = threadIdx.x & 63, wid = threadIdx.x >> 6;
  const int dir = blockIdx.x >> 2, h = blockIdx.x & 3;
  const int cl = lane & 15, kq = lane >> 4;
  const float* W = (dir ? We : Wf) + (size_t)h * FD_ * HD_;
  __hip_bfloat16* fb = Wfrag + (size_t)(dir * 4 + h) * 8192;
  #pragma unroll
  for (int db = 0; db < 4; ++db) {
    unsigned short u[8];
    #pragma unroll
    for (int j = 0; j < 8; ++j)
      u[j] = bf16rne(W[(wid * 32 + kq * 8 + j) * HD_ + db * 16 + cl]);
    uint4 pk;
    pk.x = u[0] | ((unsigned)u[1] << 16);
    pk.y = u[2] | ((unsigned)u[3] << 16);
    pk.z = u[4] | ((unsigned)u[5] << 16);
    pk.w = u[6] | ((unsigned)u[7] << 16);
    *(uint4*)(fb + ((size_t)(wid * 4 + db) * 64 + lane) * 8) = pk;
  }
  if (wid == 0) {
    const float* a1 = a_fe + h * HD_;
    const float* a2 = a_ef + h * HD_;
    float* wa = Wa + (size_t)(dir * 4 + h) * 256;
    #pragma unroll
    for (int rep = 0; rep < 2; ++rep) {
      const int f = lane + rep * 64;
      const float* wr = W + (size_t)f * HD_;
      float s1 = 0.f, s2 = 0.f;
      #pragma unroll 8
      for (int d = 0; d < HD_; ++d) {
        s1 = fmaf(wr[d], a1[d], s1);
        s2 = fmaf(wr[d], a2[d], s2);
      }
      wa[f] = s1 * LOG2E;
      wa[128 + f] = s2 * LOG2E;
    }
  }
}

// ---- MFMA proj: 16 rows/wave; fragment-tiled V + row float2 + packed col u32 ----
template<int SWAP, int NN>
__device__ __forceinline__ void proj_mfma(
    const float* __restrict__ X0, const __hip_bfloat16* __restrict__ Wfrag,
    const float* __restrict__ Wa, __hip_bfloat16* __restrict__ Vp,
    float2* __restrict__ rowO, unsigned* __restrict__ colO,
    int job, float* __restrict__ ldsX)
{
  const int lane = threadIdx.x & 63;
  const int cl = lane & 15, kq = lane >> 4;
  const int nj = NN >> 4;
  const int nt = job & (nj - 1);
  const int bh = job / nj;
  const int n0 = nt * 16;
  const int h = bh & 3, b = bh >> 2;
  const float* x0 = X0 + ((size_t)b * NN + n0 + cl) * FD_ + kq * 8;
  const __hip_bfloat16* fb = Wfrag + (size_t)((SWAP ? 4 : 0) + h) * 8192;
  const float* wa = Wa + (size_t)((SWAP ? 4 : 0) + h) * 256 + kq * 8;

  bf16x8 wf[4][4];
  #pragma unroll
  for (int ks = 0; ks < 4; ++ks)
    #pragma unroll
    for (int db = 0; db < 4; ++db)
      wf[ks][db] = *(const bf16x8*)(fb + ((size_t)(ks * 4 + db) * 64 + lane) * 8);

  bf16x8 xf[4];
  float d1 = 0.f, d2 = 0.f;
  #pragma unroll
  for (int ks = 0; ks < 4; ++ks) {
    const f32x4 xa = *(const f32x4*)(x0 + ks * 32);
    const f32x4 xb = *(const f32x4*)(x0 + ks * 32 + 4);
    const f32x4 w1a = *(const f32x4*)(wa + ks * 32);
    const f32x4 w1b = *(const f32x4*)(wa + ks * 32 + 4);
    const f32x4 w2a = *(const f32x4*)(wa + 128 + ks * 32);
    const f32x4 w2b = *(const f32x4*)(wa + 128 + ks * 32 + 4);
    #pragma unroll
    for (int i = 0; i < 4; ++i) {
      d1 = fmaf(xa[i], w1a[i], fmaf(xb[i], w1b[i], d1));
      d2 = fmaf(xa[i], w2a[i], fmaf(xb[i], w2b[i], d2));
    }
    #pragma unroll
    for (int i = 0; i < 4; ++i) {
      xf[ks][i]     = (short)bf16rne(xa[i]);
      xf[ks][i + 4] = (short)bf16rne(xb[i]);
    }
  }
  d1 += __shfl_xor(d1, 16, 64); d1 += __shfl_xor(d1, 32, 64);
  d2 += __shfl_xor(d2, 16, 64); d2 += __shfl_xor(d2, 32, 64);

  f32x4 acc[4] = {};
  #pragma unroll
  for (int ks = 0; ks < 4; ++ks)
    #pragma unroll
    for (int db = 0; db < 4; ++db)
      acc[db] = __builtin_amdgcn_mfma_f32_16x16x32_bf16(wf[ks][db], xf[ks],
                                                        acc[db], 0, 0, 0);
  #pragma unroll
  for (int db = 0; db < 4; ++db)
    *(f32x4*)(ldsX + cl * 68 + db * 16 + kq * 4) = acc[db];
  const int mt = n0 >> 6;
  #pragma unroll
  for (int c = 0; c < 2; ++c) {
    const int nb = n0 + c * 8;
    const int ks2 = (nb >> 5) & 1, q2 = (nb >> 3) & 3;
    unsigned short u[8];
    #pragma unroll
    for (int j = 0; j < 8; ++j)
      u[j] = bf16rne(ldsX[(c * 8 + j) * 68 + lane]);
    uint4 pk;
    pk.x = u[0] | ((unsigned)u[1] << 16);
    pk.y = u[2] | ((unsigned)u[3] << 16);
    pk.z = u[4] | ((unsigned)u[5] << 16);
    pk.w = u[6] | ((unsigned)u[7] << 16);
    *(uint4*)(Vp + ((size_t)((mt * 8 + ks2 * 4 + (lane >> 4)) * 64
                             + q2 * 16 + (lane & 15))) * 8) = pk;
  }
  if (kq == 0) {
    const float rd = SWAP ? d2 : d1;
    const float cd = SWAP ? d1 : d2;
    float2 rp;
    rp.x = exp2f(rd - KH);
    rp.y = exp2f(0.2f * rd - KH);
    const size_t idxn = (size_t)bh * NN + n0 + cl;
    rowO[idxn] = rp;
    colO[idxn] = (unsigned)bf16rne(exp2f(cd - KH)) |
                 ((unsigned)bf16rne(exp2f(0.2f * cd - KH)) << 16);
  }
}

// ---- bitpack: transposed bits_t[mt][n] ----
__device__ __forceinline__ void bitpack_body(
    const int* __restrict__ adj_fe, const int* __restrict__ adj_ef,
    u64* __restrict__ btfe, u64* __restrict__ btef, int id)
{
  const int lane = threadIdx.x & 63;
  const int* adj; u64* bt; int N, M, mt, g;
  if (id < 8192) {                            // fe: 64 mt x 128 g
    adj = adj_fe; bt = btfe; N = NF_; M = NE_;
    mt = id >> 7; g = id & 127;
  } else {                                    // ef: 32 mt x 256 g
    const int k = id - 8192;
    adj = adj_ef; bt = btef; N = NE_; M = NF_;
    mt = k >> 8; g = k & 255;
  }
  const int* base = adj + (size_t)(g * 16) * M + mt * 64 + lane;
  int v[16];
  #pragma unroll
  for (int r = 0; r < 16; ++r) v[r] = base[(size_t)r * M];
  u64 mine = 0;
  #pragma unroll
  for (int r = 0; r < 16; ++r) {
    u64 msk = __ballot(v[r] != 0);
    if (lane == r) mine = msk;
  }
  if (lane < 16) bt[(size_t)mt * N + g * 16 + lane] = mine;
}

// ---- fused prep ----
__global__ __launch_bounds__(256) void prep_kernel(
    const float* __restrict__ F0, const float* __restrict__ E0,
    const int* __restrict__ adj_fe, const int* __restrict__ adj_ef,
    const __hip_bfloat16* __restrict__ Wfrag, const float* __restrict__ Wa,
    __hip_bfloat16* __restrict__ Ftl, __hip_bfloat16* __restrict__ Etl,
    float2* __restrict__ rowF, unsigned* __restrict__ colF,
    float2* __restrict__ rowE, unsigned* __restrict__ colE,
    u64* __restrict__ btfe, u64* __restrict__ btef)
{
  __shared__ __align__(16) float ldsX[4][16 * 68];
  const int blk = blockIdx.x;
  const int wid = threadIdx.x >> 6;
  if (blk < 4096) {
    bitpack_body(adj_fe, adj_ef, btfe, btef, blk * 4 + wid);
  } else {
    const int job = (blk - 4096) * 4 + wid;   // [0, 3072)
    if (job < 1024) {
      const int bh = job >> 7;
      proj_mfma<0, NF_>(F0, Wfrag, Wa, Ftl + (size_t)bh * 32 * 4096,
                        rowF, colF, job, ldsX[wid]);
    } else {
      const int j2 = job - 1024;
      const int bh = j2 >> 8;
      proj_mfma<1, NE_>(E0, Wfrag, Wa, Etl + (size_t)bh * 64 * 4096,
                        rowE, colE, j2, ldsX[wid]);
    }
  }
}

// ---- attention: block = 64 rows x full M. All 4 waves share the SAME
// V tile, staged once per block into double-buffered LDS (global->reg->
// LDS, T14 split, 1 barrier/tile). Wave owns a full 16-row fragment ->
// no cross-wave reduction epilogue. Cuts V L2 traffic 4x (R12/R13 nulls
// showed the kernel is L2-BW-bound, not latency/VALU-bound). ----
template<int TQ, int NN>
__device__ __forceinline__ void attn_wave_lds(
    const char* __restrict__ vtile, const unsigned* __restrict__ colp,
    const u64* __restrict__ bt, float Ea, float Ga, int nrow16,
    char* __restrict__ lds0, char* __restrict__ lds1,
    int lane, int wid, int cl, int kq,
    f32x4 (&accT)[4], f32x4 &accS)
{
  bf16x8 ones;
  #pragma unroll
  for (int i = 0; i < 8; ++i) ones[i] = (short)0x3F80;  // bf16 1.0

  const unsigned* cp = colp + kq * 8;
  const u64* bp = bt + nrow16 + cl;
  const int shk = kq * 8;
  const int soff = wid * 2048 + lane * 16;   // this thread's 2x16B stage slice
  const char* gp = vtile + soff;

  uint4 sr0, sr1;
  // prologue: stage tile 0
  sr0 = *(const uint4*)(gp);
  sr1 = *(const uint4*)(gp + 1024);
  *(uint4*)(lds0 + soff) = sr0;
  *(uint4*)(lds0 + soff + 1024) = sr1;
  __syncthreads();

  #pragma unroll 1
  for (int t = 0; t < TQ; ++t) {
    const char* cb = (t & 1) ? lds1 : lds0;
    char* nb = (t & 1) ? lds0 : lds1;
    // issue next tile's global loads early (land under this tile's compute)
    if (t + 1 < TQ) {
      const char* gn = gp + (size_t)(t + 1) * 8192;
      sr0 = *(const uint4*)(gn);
      sr1 = *(const uint4*)(gn + 1024);
    }
    // small per-wave loads (L2-resident, broadcast-coalesced)
    const uint32x4 cc0 = *(const uint32x4*)(cp);
    const uint32x4 cc1 = *(const uint32x4*)(cp + 4);
    const uint32x4 cc2 = *(const uint32x4*)(cp + 32);
    const uint32x4 cc3 = *(const uint32x4*)(cp + 36);
    const u64 s0 = (*bp) >> shk;
    cp += 64; bp += NN;
    // V fragments from LDS (conflict-free consecutive b128)
    const bf16x8 vf0 = *(const bf16x8*)(cb + lane * 16);
    const bf16x8 vf1 = *(const bf16x8*)(cb + 1024 + lane * 16);
    const bf16x8 vf2 = *(const bf16x8*)(cb + 2048 + lane * 16);
    const bf16x8 vf3 = *(const bf16x8*)(cb + 3072 + lane * 16);
    const bf16x8 vf4 = *(const bf16x8*)(cb + 4096 + lane * 16);
    const bf16x8 vf5 = *(const bf16x8*)(cb + 5120 + lane * 16);
    const bf16x8 vf6 = *(const bf16x8*)(cb + 6144 + lane * 16);
    const bf16x8 vf7 = *(const bf16x8*)(cb + 7168 + lane * 16);

    bf16x8 pf;
    unsigned mw;
#define PJ(CC, JB, J) {                                                   \
      const unsigned cv = (CC)[J];                                        \
      const float Eb = __uint_as_float(cv << 16);                         \
      const float Gb = __uint_as_float(cv & 0xffff0000u);                 \
      float e = fmaxf(Ea * Eb, Ga * Gb);       /* exp2(lrelu(s')-C2) */   \
      const int sm = ((int)(mw << (31 - (JB + J)))) >> 31;                \
      e = __int_as_float(__float_as_int(e) & sm);                         \
      __hip_bfloat16 hb = __float2bfloat16(e);                            \
      pf[JB + J] = *(const short*)&hb;                                    \
    }
    // ---- ks = 0 ----
    mw = (unsigned)s0;
    PJ(cc0, 0, 0) PJ(cc0, 0, 1) PJ(cc0, 0, 2) PJ(cc0, 0, 3)
    PJ(cc1, 4, 0) PJ(cc1, 4, 1) PJ(cc1, 4, 2) PJ(cc1, 4, 3)
    accS = __builtin_amdgcn_mfma_f32_16x16x32_bf16(pf, ones, accS, 0, 0, 0);
    accT[0] = __builtin_amdgcn_mfma_f32_16x16x32_bf16(pf, vf0, accT[0], 0, 0, 0);
    accT[1] = __builtin_amdgcn_mfma_f32_16x16x32_bf16(pf, vf1, accT[1], 0, 0, 0);
    accT[2] = __builtin_amdgcn_mfma_f32_16x16x32_bf16(pf, vf2, accT[2], 0, 0, 0);
    accT[3] = __builtin_amdgcn_mfma_f32_16x16x32_bf16(pf, vf3, accT[3], 0, 0, 0);
    // ---- ks = 1 ----
    mw = (unsigned)(s0 >> 32);
    PJ(cc2, 0, 0) PJ(cc2, 0, 1) PJ(cc2, 0, 2) PJ(cc2, 0, 3)
    PJ(cc3, 4, 0) PJ(cc3, 4, 1) PJ(cc3, 4, 2) PJ(cc3, 4, 3)
    accS = __builtin_amdgcn_mfma_f32_16x16x32_bf16(pf, ones, accS, 0, 0, 0);
    accT[0] = __builtin_amdgcn_mfma_f32_16x16x32_bf16(pf, vf4, accT[0], 0, 0, 0);
    accT[1] = __builtin_amdgcn_mfma_f32_16x16x32_bf16(pf, vf5, accT[1], 0, 0, 0);
    accT[2] = __builtin_amdgcn_mfma_f32_16x16x32_bf16(pf, vf6, accT[2], 0, 0, 0);
    accT[3] = __builtin_amdgcn_mfma_f32_16x16x32_bf16(pf, vf7, accT[3], 0, 0, 0);
#undef PJ
    // write next tile to the other LDS buffer (vmcnt wait folds here),
    // then one barrier: makes nb visible AND protects cb from t+1's write.
    if (t + 1 < TQ) {
      *(uint4*)(nb + soff) = sr0;
      *(uint4*)(nb + soff + 1024) = sr1;
    }
    __syncthreads();
  }
}

// fe blocks [0,256): 8 bh x 32 rowblocks; ef [256,768): 8 bh x 64 rowblocks
__global__ __launch_bounds__(256, 2) void attn_kernel(
    const __hip_bfloat16* __restrict__ Ftl, const __hip_bfloat16* __restrict__ Etl,
    const float2* __restrict__ rowF, const unsigned* __restrict__ colF,
    const float2* __restrict__ rowE, const unsigned* __restrict__ colE,
    const u64* __restrict__ btfe, const u64* __restrict__ btef,
    float* __restrict__ out)
{
  __shared__ __align__(16) char lbuf0[8192];
  __shared__ __align__(16) char lbuf1[8192];

  const int lane = threadIdx.x & 63;
  const int wid  = threadIdx.x >> 6;
  const int cl = lane & 15, kq = lane >> 4;
  const int blk = blockIdx.x;

  int N, bh, nrow16;
  float* obase;
  bool relu;
  f32x4 accT[4] = {};
  f32x4 accS = {0.f, 0.f, 0.f, 0.f};

  if (blk < 256) {             // fe: V = E (64 tiles), rows from F
    bh = blk & 7;
    nrow16 = (blk >> 3) * 64 + wid * 16;
    N = NF_;
    const float2 rp = rowF[(size_t)bh * NF_ + nrow16 + cl];
    attn_wave_lds<64, NF_>((const char*)(Etl + (size_t)bh * 64 * 4096),
                           colE + (size_t)bh * NE_, btfe,
                           rp.x, rp.y, nrow16, lbuf0, lbuf1,
                           lane, wid, cl, kq, accT, accS);
    obase = out; relu = false;
  } else {                     // ef: V = F (32 tiles), rows from E
    const int k2 = blk - 256;
    bh = k2 & 7;
    nrow16 = (k2 >> 3) * 64 + wid * 16;
    N = NE_;
    const float2 rp = rowE[(size_t)bh * NE_ + nrow16 + cl];
    attn_wave_lds<32, NE_>((const char*)(Ftl + (size_t)bh * 32 * 4096),
                           colF + (size_t)bh * NF_, btef,
                           rp.x, rp.y, nrow16, lbuf0, lbuf1,
                           lane, wid, cl, kq, accT, accS);
    obase = out + (size_t)B_ * NF_ * 256; relu = true;
  }

  // direct epilogue: this wave owns rows nrow16..nrow16+15 completely.
  const int b = bh >> 2, h = bh & 3;
  float* orow = obase + ((size_t)b * N + nrow16 + kq * 4) * 256 + h * HD_ + cl;
  #pragma unroll
  for (int reg = 0; reg < 4; ++reg) {
    const float inv = 1.0f / accS[reg];
    #pragma unroll
    for (int db = 0; db < 4; ++db) {
      float v = accT[db][reg] * inv;
      if (relu) v = fmaxf(v, 0.0f);
      orow[reg * 256 + db * 16] = v;
    }
  }
}

// in-place softmax over the 256-channel axis
__global__ __launch_bounds__(256) void softmax256_kernel(float* __restrict__ io)
{
  const int t = threadIdx.x;
  const int lane = t & 63, wid = t >> 6;
  float v = io[(long)blockIdx.x * 256 + t];
  __shared__ float red[8];
  float m = wave_max64(v);
  if (lane == 0) red[wid] = m;
  __syncthreads();
  m = fmaxf(fmaxf(red[0], red[1]), fmaxf(red[2], red[3]));
  float e = __expf(v - m);
  float s = wave_sum64(e);
  if (lane == 0) red[4 + wid] = s;
  __syncthreads();
  s = (red[4] + red[5]) + (red[6] + red[7]);
  io[(long)blockIdx.x * 256 + t] = e / s;
}

extern "C" void kernel_launch(void* const* d_in, const int* in_sizes, int n_in,
                              void* d_out, int out_size, void* d_ws, size_t ws_size,
                              hipStream_t stream)
{
  const float* F0   = (const float*)d_in[0];
  const float* E0   = (const float*)d_in[1];
  const int* adj_fe = (const int*)d_in[2];
  const int* adj_ef = (const int*)d_in[3];
  const float* Wf   = (const float*)d_in[4];
  const float* We   = (const float*)d_in[5];
  const float* a_fe = (const float*)d_in[6];
  const float* a_ef = (const float*)d_in[7];
  float* out = (float*)d_out;

  char* ws = (char*)d_ws;
  float2* rowF = (float2*)ws;                               // 128KB
  float2* rowE = (float2*)(ws + (128 << 10));               // 256KB
  unsigned* colF = (unsigned*)(ws + (384 << 10));           // 64KB
  unsigned* colE = (unsigned*)(ws + (448 << 10));           // 128KB
  u64* btfe = (u64*)(ws + (576 << 10));                     // 1MB
  u64* btef = btfe + (size_t)NF_ * (NE_ / 64);              // 1MB
  __hip_bfloat16* Ftl = (__hip_bfloat16*)(btef + (size_t)NE_ * (NF_ / 64)); // 2MB
  __hip_bfloat16* Etl = Ftl + (size_t)8 * 32 * 4096;        // 4MB
  __hip_bfloat16* Wfrag = Etl + (size_t)8 * 64 * 4096;
  float* Wa = (float*)(Wfrag + (size_t)8 * 8192);

  pre_kernel<<<8, 256, 0, stream>>>(Wf, We, a_fe, a_ef, Wfrag, Wa);
  prep_kernel<<<4864, 256, 0, stream>>>(F0, E0, adj_fe, adj_ef, Wfrag, Wa,
                                        Ftl, Etl, rowF, colF, rowE, colE,
                                        btfe, btef);
  attn_kernel<<<768, 256, 0, stream>>>(Ftl, Etl, rowF, colF, rowE, colE,
                                       btfe, btef, out);
  softmax256_kernel<<<B_ * NF_, 256, 0, stream>>>(out);
}

// Round 16
// 88.712 us; speedup vs baseline: 1.0845x; 1.0845x over previous
//
#include <hip/hip_runtime.h>
#include <hip/hip_bf16.h>
#include <stdint.h>

#define B_  2
#define NF_ 2048
#define NE_ 4096
#define FD_ 128
#define HD_ 64
#define H_  4

#define LOG2E 1.44269504f
#define KH2   4.0f   // per-factor log2 offset; winner products in [2^-12, 2^13] -> f16 normal

typedef unsigned long long u64;
typedef __attribute__((ext_vector_type(4))) float f32x4;
typedef __attribute__((ext_vector_type(8))) short bf16x8;
typedef __attribute__((ext_vector_type(8))) _Float16 f16x8;
typedef __attribute__((ext_vector_type(2))) _Float16 f16x2;
typedef __attribute__((ext_vector_type(4))) unsigned uint32x4;

__device__ __forceinline__ float wave_sum64(float v) {
  #pragma unroll
  for (int m = 32; m >= 1; m >>= 1) v += __shfl_xor(v, m, 64);
  return v;
}
__device__ __forceinline__ float wave_max64(float v) {
  #pragma unroll
  for (int m = 32; m >= 1; m >>= 1) v = fmaxf(v, __shfl_xor(v, m, 64));
  return v;
}
__device__ __forceinline__ unsigned short bf16rne(float x) {
  unsigned u = __float_as_uint(x);
  return (unsigned short)((u + 0x7FFFu + ((u >> 16) & 1u)) >> 16);
}
__device__ __forceinline__ f16x2 u2h2(unsigned u) {
  union { unsigned u; f16x2 h; } c; c.u = u; return c.h;
}
__device__ __forceinline__ unsigned h22u(f16x2 h) {
  union { unsigned u; f16x2 h; } c; c.h = h; return c.u;
}
__device__ __forceinline__ unsigned short f16b(float x) {
  union { _Float16 h; unsigned short s; } c; c.h = (_Float16)x; return c.s;
}

// ---- pre: tile W into A-fragment bf16 layout + Wa = (W @ a) * log2e ----
__global__ __launch_bounds__(256) void pre_kernel(
    const float* __restrict__ Wf, const float* __restrict__ We,
    const float* __restrict__ a_fe, const float* __restrict__ a_ef,
    __hip_bfloat16* __restrict__ Wfrag, float* __restrict__ Wa)
{
  const int lane = threadIdx.x & 63, wid = threadIdx.x >> 6;
  const int dir = blockIdx.x >> 2, h = blockIdx.x & 3;
  const int cl = lane & 15, kq = lane >> 4;
  const float* W = (dir ? We : Wf) + (size_t)h * FD_ * HD_;
  __hip_bfloat16* fb = Wfrag + (size_t)(dir * 4 + h) * 8192;
  #pragma unroll
  for (int db = 0; db < 4; ++db) {
    unsigned short u[8];
    #pragma unroll
    for (int j = 0; j < 8; ++j)
      u[j] = bf16rne(W[(wid * 32 + kq * 8 + j) * HD_ + db * 16 + cl]);
    uint4 pk;
    pk.x = u[0] | ((unsigned)u[1] << 16);
    pk.y = u[2] | ((unsigned)u[3] << 16);
    pk.z = u[4] | ((unsigned)u[5] << 16);
    pk.w = u[6] | ((unsigned)u[7] << 16);
    *(uint4*)(fb + ((size_t)(wid * 4 + db) * 64 + lane) * 8) = pk;
  }
  if (wid == 0) {
    const float* a1 = a_fe + h * HD_;
    const float* a2 = a_ef + h * HD_;
    float* wa = Wa + (size_t)(dir * 4 + h) * 256;
    #pragma unroll
    for (int rep = 0; rep < 2; ++rep) {
      const int f = lane + rep * 64;
      const float* wr = W + (size_t)f * HD_;
      float s1 = 0.f, s2 = 0.f;
      #pragma unroll 8
      for (int d = 0; d < HD_; ++d) {
        s1 = fmaf(wr[d], a1[d], s1);
        s2 = fmaf(wr[d], a2[d], s2);
      }
      wa[f] = s1 * LOG2E;
      wa[128 + f] = s2 * LOG2E;
    }
  }
}

// ---- MFMA proj: 16 rows/wave; fragment-tiled f16 V + f32 row pair + f16 col E/G ----
template<int SWAP, int NN>
__device__ __forceinline__ void proj_mfma(
    const float* __restrict__ X0, const __hip_bfloat16* __restrict__ Wfrag,
    const float* __restrict__ Wa, unsigned short* __restrict__ Vp,
    float2* __restrict__ rowO, unsigned short* __restrict__ colEO,
    unsigned short* __restrict__ colGO, int job, float* __restrict__ ldsX)
{
  const int lane = threadIdx.x & 63;
  const int cl = lane & 15, kq = lane >> 4;
  const int nj = NN >> 4;
  const int nt = job & (nj - 1);
  const int bh = job / nj;
  const int n0 = nt * 16;
  const int h = bh & 3, b = bh >> 2;
  const float* x0 = X0 + ((size_t)b * NN + n0 + cl) * FD_ + kq * 8;
  const __hip_bfloat16* fb = Wfrag + (size_t)((SWAP ? 4 : 0) + h) * 8192;
  const float* wa = Wa + (size_t)((SWAP ? 4 : 0) + h) * 256 + kq * 8;

  bf16x8 wf[4][4];
  #pragma unroll
  for (int ks = 0; ks < 4; ++ks)
    #pragma unroll
    for (int db = 0; db < 4; ++db)
      wf[ks][db] = *(const bf16x8*)(fb + ((size_t)(ks * 4 + db) * 64 + lane) * 8);

  bf16x8 xf[4];
  float d1 = 0.f, d2 = 0.f;
  #pragma unroll
  for (int ks = 0; ks < 4; ++ks) {
    const f32x4 xa = *(const f32x4*)(x0 + ks * 32);
    const f32x4 xb = *(const f32x4*)(x0 + ks * 32 + 4);
    const f32x4 w1a = *(const f32x4*)(wa + ks * 32);
    const f32x4 w1b = *(const f32x4*)(wa + ks * 32 + 4);
    const f32x4 w2a = *(const f32x4*)(wa + 128 + ks * 32);
    const f32x4 w2b = *(const f32x4*)(wa + 128 + ks * 32 + 4);
    #pragma unroll
    for (int i = 0; i < 4; ++i) {
      d1 = fmaf(xa[i], w1a[i], fmaf(xb[i], w1b[i], d1));
      d2 = fmaf(xa[i], w2a[i], fmaf(xb[i], w2b[i], d2));
    }
    #pragma unroll
    for (int i = 0; i < 4; ++i) {
      xf[ks][i]     = (short)bf16rne(xa[i]);
      xf[ks][i + 4] = (short)bf16rne(xb[i]);
    }
  }
  d1 += __shfl_xor(d1, 16, 64); d1 += __shfl_xor(d1, 32, 64);
  d2 += __shfl_xor(d2, 16, 64); d2 += __shfl_xor(d2, 32, 64);

  f32x4 acc[4] = {};
  #pragma unroll
  for (int ks = 0; ks < 4; ++ks)
    #pragma unroll
    for (int db = 0; db < 4; ++db)
      acc[db] = __builtin_amdgcn_mfma_f32_16x16x32_bf16(wf[ks][db], xf[ks],
                                                        acc[db], 0, 0, 0);
  #pragma unroll
  for (int db = 0; db < 4; ++db)
    *(f32x4*)(ldsX + cl * 68 + db * 16 + kq * 4) = acc[db];
  const int mt = n0 >> 6;
  #pragma unroll
  for (int c = 0; c < 2; ++c) {
    const int nb = n0 + c * 8;
    const int ks2 = (nb >> 5) & 1, q2 = (nb >> 3) & 3;
    unsigned short u[8];
    #pragma unroll
    for (int j = 0; j < 8; ++j)
      u[j] = f16b(ldsX[(c * 8 + j) * 68 + lane]);
    uint4 pk;
    pk.x = u[0] | ((unsigned)u[1] << 16);
    pk.y = u[2] | ((unsigned)u[3] << 16);
    pk.z = u[4] | ((unsigned)u[5] << 16);
    pk.w = u[6] | ((unsigned)u[7] << 16);
    *(uint4*)(Vp + ((size_t)((mt * 8 + ks2 * 4 + (lane >> 4)) * 64
                             + q2 * 16 + (lane & 15))) * 8) = pk;
  }
  if (kq == 0) {
    const float rd = SWAP ? d2 : d1;
    const float cd = SWAP ? d1 : d2;
    float2 rp;
    rp.x = exp2f(rd - KH2);
    rp.y = exp2f(0.2f * rd - KH2);
    const size_t idxn = (size_t)bh * NN + n0 + cl;
    rowO[idxn] = rp;
    colEO[idxn] = f16b(exp2f(cd - KH2));
    colGO[idxn] = f16b(exp2f(0.2f * cd - KH2));
  }
}

// ---- bitpack: transposed bits_t[mt][n] ----
__device__ __forceinline__ void bitpack_body(
    const int* __restrict__ adj_fe, const int* __restrict__ adj_ef,
    u64* __restrict__ btfe, u64* __restrict__ btef, int id)
{
  const int lane = threadIdx.x & 63;
  const int* adj; u64* bt; int N, M, mt, g;
  if (id < 8192) {                            // fe: 64 mt x 128 g
    adj = adj_fe; bt = btfe; N = NF_; M = NE_;
    mt = id >> 7; g = id & 127;
  } else {                                    // ef: 32 mt x 256 g
    const int k = id - 8192;
    adj = adj_ef; bt = btef; N = NE_; M = NF_;
    mt = k >> 8; g = k & 255;
  }
  const int* base = adj + (size_t)(g * 16) * M + mt * 64 + lane;
  int v[16];
  #pragma unroll
  for (int r = 0; r < 16; ++r) v[r] = base[(size_t)r * M];
  u64 mine = 0;
  #pragma unroll
  for (int r = 0; r < 16; ++r) {
    u64 msk = __ballot(v[r] != 0);
    if (lane == r) mine = msk;
  }
  if (lane < 16) bt[(size_t)mt * N + g * 16 + lane] = mine;
}

// ---- fused prep ----
__global__ __launch_bounds__(256) void prep_kernel(
    const float* __restrict__ F0, const float* __restrict__ E0,
    const int* __restrict__ adj_fe, const int* __restrict__ adj_ef,
    const __hip_bfloat16* __restrict__ Wfrag, const float* __restrict__ Wa,
    unsigned short* __restrict__ Ftl, unsigned short* __restrict__ Etl,
    float2* __restrict__ rowF, unsigned short* __restrict__ colEF,
    unsigned short* __restrict__ colGF, float2* __restrict__ rowE,
    unsigned short* __restrict__ colEE, unsigned short* __restrict__ colGE,
    u64* __restrict__ btfe, u64* __restrict__ btef)
{
  __shared__ __align__(16) float ldsX[4][16 * 68];
  const int blk = blockIdx.x;
  const int wid = threadIdx.x >> 6;
  if (blk < 4096) {
    bitpack_body(adj_fe, adj_ef, btfe, btef, blk * 4 + wid);
  } else {
    const int job = (blk - 4096) * 4 + wid;   // [0, 3072)
    if (job < 1024) {
      const int bh = job >> 7;
      proj_mfma<0, NF_>(F0, Wfrag, Wa, Ftl + (size_t)bh * 32 * 4096,
                        rowF, colEF, colGF, job, ldsX[wid]);
    } else {
      const int j2 = job - 1024;
      const int bh = j2 >> 8;
      proj_mfma<1, NE_>(E0, Wfrag, Wa, Etl + (size_t)bh * 64 * 4096,
                        rowE, colEE, colGE, j2, ldsX[wid]);
    }
  }
}

// ---- attention inner loop: 1 fragment, R11 structure, packed-f16 P build.
// Per pair: v_pk_mul_f16 x2 + v_pk_max_f16 + sbfe x2 + and; masked u32 IS
// the fragment word (no cvt, no insert). Same 13 loads/tile as R11. ----
template<int TQ, int NN>
__device__ __forceinline__ void attn_wave(
    const unsigned short* __restrict__ vpp, const unsigned short* __restrict__ colE,
    const unsigned short* __restrict__ colG, const u64* __restrict__ bt,
    float Ea, float Ga, int n0, int mt0, int cl, int kq,
    f32x4 (&accT)[4], f32x4 &accS)
{
  const int lane = threadIdx.x & 63;
  f16x8 ones;
  #pragma unroll
  for (int i = 0; i < 8; ++i) ones[i] = (_Float16)1.0f;

  const unsigned short* tb = vpp + (size_t)mt0 * 4096 + (size_t)lane * 8;
  const unsigned short* cpE = colE + mt0 * 64 + kq * 8;
  const unsigned short* cpG = colG + mt0 * 64 + kq * 8;
  const u64* bp = bt + (size_t)mt0 * NN + n0 + cl;
  const int shk = kq * 8;
  const f16x2 Ea2 = {(_Float16)Ea, (_Float16)Ea};
  const f16x2 Ga2 = {(_Float16)Ga, (_Float16)Ga};

  #pragma unroll 1
  for (int t = 0; t < TQ; ++t) {
    const f16x8 vf0 = *(const f16x8*)(tb);
    const f16x8 vf1 = *(const f16x8*)(tb + 512);
    const f16x8 vf2 = *(const f16x8*)(tb + 1024);
    const f16x8 vf3 = *(const f16x8*)(tb + 1536);
    const f16x8 vf4 = *(const f16x8*)(tb + 2048);
    const f16x8 vf5 = *(const f16x8*)(tb + 2560);
    const f16x8 vf6 = *(const f16x8*)(tb + 3072);
    const f16x8 vf7 = *(const f16x8*)(tb + 3584);
    const uint32x4 ceA = *(const uint32x4*)(cpE);        // cols kq*8..+7, ks=0
    const uint32x4 ceB = *(const uint32x4*)(cpE + 32);   // ks=1
    const uint32x4 cgA = *(const uint32x4*)(cpG);
    const uint32x4 cgB = *(const uint32x4*)(cpG + 32);
    const u64 s0 = (*bp) >> shk;
    tb += 4096; cpE += 64; cpG += 64; bp += NN;

    uint32x4 pfu;
    unsigned mw;

#define PP(EB, GB, P) {                                                   \
      const f16x2 eb = u2h2((EB)[P]);                                     \
      const f16x2 gb = u2h2((GB)[P]);                                     \
      const f16x2 pm = __builtin_elementwise_max(Ea2 * eb, Ga2 * gb);     \
      const int m0 = __builtin_amdgcn_sbfe((int)mw, 2 * (P), 1);          \
      const int m1 = __builtin_amdgcn_sbfe((int)mw, 2 * (P) + 1, 1);      \
      const unsigned msk = ((unsigned)m0 & 0xFFFFu) |                     \
                           ((unsigned)m1 & 0xFFFF0000u);                  \
      pfu[P] = h22u(pm) & msk;                                            \
    }

    // ---- ks = 0 ----
    mw = (unsigned)s0;
    PP(ceA, cgA, 0) PP(ceA, cgA, 1) PP(ceA, cgA, 2) PP(ceA, cgA, 3)
    {
      union { uint32x4 u; f16x8 h; } pc; pc.u = pfu;
      const f16x8 pf = pc.h;
      accS = __builtin_amdgcn_mfma_f32_16x16x32_f16(pf, ones, accS, 0, 0, 0);
      accT[0] = __builtin_amdgcn_mfma_f32_16x16x32_f16(pf, vf0, accT[0], 0, 0, 0);
      accT[1] = __builtin_amdgcn_mfma_f32_16x16x32_f16(pf, vf1, accT[1], 0, 0, 0);
      accT[2] = __builtin_amdgcn_mfma_f32_16x16x32_f16(pf, vf2, accT[2], 0, 0, 0);
      accT[3] = __builtin_amdgcn_mfma_f32_16x16x32_f16(pf, vf3, accT[3], 0, 0, 0);
    }
    // ---- ks = 1 ----
    mw = (unsigned)(s0 >> 32);
    PP(ceB, cgB, 0) PP(ceB, cgB, 1) PP(ceB, cgB, 2) PP(ceB, cgB, 3)
    {
      union { uint32x4 u; f16x8 h; } pc; pc.u = pfu;
      const f16x8 pf = pc.h;
      accS = __builtin_amdgcn_mfma_f32_16x16x32_f16(pf, ones, accS, 0, 0, 0);
      accT[0] = __builtin_amdgcn_mfma_f32_16x16x32_f16(pf, vf4, accT[0], 0, 0, 0);
      accT[1] = __builtin_amdgcn_mfma_f32_16x16x32_f16(pf, vf5, accT[1], 0, 0, 0);
      accT[2] = __builtin_amdgcn_mfma_f32_16x16x32_f16(pf, vf6, accT[2], 0, 0, 0);
      accT[3] = __builtin_amdgcn_mfma_f32_16x16x32_f16(pf, vf7, accT[3], 0, 0, 0);
    }
#undef PP
  }
}

// ---- fused attention: block = 16 rows, 4 waves split M; XCD-local bh ----
__global__ __launch_bounds__(256) void attn_kernel(
    const unsigned short* __restrict__ Ftl, const unsigned short* __restrict__ Etl,
    const float2* __restrict__ rowF, const unsigned short* __restrict__ colEF,
    const unsigned short* __restrict__ colGF, const float2* __restrict__ rowE,
    const unsigned short* __restrict__ colEE, const unsigned short* __restrict__ colGE,
    const u64* __restrict__ btfe, const u64* __restrict__ btef,
    float* __restrict__ out)
{
  __shared__ __align__(16) float ldsO[4 * 4 * 64 * 4];  // 16KB
  __shared__ float ldsS[4 * 16];

  const int lane = threadIdx.x & 63;
  const int wid  = threadIdx.x >> 6;
  const int cl = lane & 15, kq = lane >> 4;
  const int blk = blockIdx.x;

  int N, bh, n0;
  float* obase;
  bool relu;
  f32x4 accT[4] = {};
  f32x4 accS = {0.f, 0.f, 0.f, 0.f};

  if (blk < 1024) {            // fe
    bh = blk & 7;
    n0 = (blk >> 3) * 16;
    N = NF_;
    const float2 rp = rowF[(size_t)bh * NF_ + n0 + cl];
    attn_wave<16, NF_>(Etl + (size_t)bh * 64 * 4096,
                       colEE + (size_t)bh * NE_, colGE + (size_t)bh * NE_,
                       btfe, rp.x, rp.y, n0, wid * 16, cl, kq, accT, accS);
    obase = out; relu = false;
  } else {                     // ef
    const int k2 = blk - 1024;
    bh = k2 & 7;
    n0 = (k2 >> 3) * 16;
    N = NE_;
    const float2 rp = rowE[(size_t)bh * NE_ + n0 + cl];
    attn_wave<8, NE_>(Ftl + (size_t)bh * 32 * 4096,
                      colEF + (size_t)bh * NF_, colGF + (size_t)bh * NF_,
                      btef, rp.x, rp.y, n0, wid * 8, cl, kq, accT, accS);
    obase = out + (size_t)B_ * NF_ * 256; relu = true;
  }

  #pragma unroll
  for (int db = 0; db < 4; ++db)
    *(f32x4*)&ldsO[((db * 4 + wid) * 64 + lane) * 4] = accT[db];
  if (cl == 0) {
    #pragma unroll
    for (int reg = 0; reg < 4; ++reg)
      ldsS[wid * 16 + kq * 4 + reg] = accS[reg];
  }
  __syncthreads();

  f32x4 osum = {0.f, 0.f, 0.f, 0.f};
  #pragma unroll
  for (int s = 0; s < 4; ++s)
    osum += *(const f32x4*)&ldsO[((wid * 4 + s) * 64 + lane) * 4];
  float stot[4];
  #pragma unroll
  for (int reg = 0; reg < 4; ++reg) {
    stot[reg] = 0.f;
    #pragma unroll
    for (int s = 0; s < 4; ++s) stot[reg] += ldsS[s * 16 + kq * 4 + reg];
  }
  const int b = bh >> 2, h = bh & 3;
  float* orow = obase + ((size_t)b * N + n0 + kq * 4) * 256 + h * HD_ + wid * 16 + cl;
  #pragma unroll
  for (int reg = 0; reg < 4; ++reg) {
    float v = osum[reg] / stot[reg];
    if (relu) v = fmaxf(v, 0.0f);
    orow[reg * 256] = v;
  }
}

// in-place softmax over the 256-channel axis
__global__ __launch_bounds__(256) void softmax256_kernel(float* __restrict__ io)
{
  const int t = threadIdx.x;
  const int lane = t & 63, wid = t >> 6;
  float v = io[(long)blockIdx.x * 256 + t];
  __shared__ float red[8];
  float m = wave_max64(v);
  if (lane == 0) red[wid] = m;
  __syncthreads();
  m = fmaxf(fmaxf(red[0], red[1]), fmaxf(red[2], red[3]));
  float e = __expf(v - m);
  float s = wave_sum64(e);
  if (lane == 0) red[4 + wid] = s;
  __syncthreads();
  s = (red[4] + red[5]) + (red[6] + red[7]);
  io[(long)blockIdx.x * 256 + t] = e / s;
}

extern "C" void kernel_launch(void* const* d_in, const int* in_sizes, int n_in,
                              void* d_out, int out_size, void* d_ws, size_t ws_size,
                              hipStream_t stream)
{
  const float* F0   = (const float*)d_in[0];
  const float* E0   = (const float*)d_in[1];
  const int* adj_fe = (const int*)d_in[2];
  const int* adj_ef = (const int*)d_in[3];
  const float* Wf   = (const float*)d_in[4];
  const float* We   = (const float*)d_in[5];
  const float* a_fe = (const float*)d_in[6];
  const float* a_ef = (const float*)d_in[7];
  float* out = (float*)d_out;

  char* ws = (char*)d_ws;
  float2* rowF = (float2*)ws;                               // 128KB
  float2* rowE = (float2*)(ws + (128 << 10));               // 256KB
  unsigned short* colEF = (unsigned short*)(ws + (384 << 10));  // 32KB
  unsigned short* colGF = (unsigned short*)(ws + (416 << 10));  // 32KB
  unsigned short* colEE = (unsigned short*)(ws + (448 << 10));  // 64KB
  unsigned short* colGE = (unsigned short*)(ws + (512 << 10));  // 64KB
  u64* btfe = (u64*)(ws + (576 << 10));                     // 1MB
  u64* btef = btfe + (size_t)NF_ * (NE_ / 64);              // 1MB
  unsigned short* Ftl = (unsigned short*)(btef + (size_t)NE_ * (NF_ / 64)); // 2MB
  unsigned short* Etl = Ftl + (size_t)8 * 32 * 4096;        // 4MB
  __hip_bfloat16* Wfrag = (__hip_bfloat16*)(Etl + (size_t)8 * 64 * 4096);
  float* Wa = (float*)(Wfrag + (size_t)8 * 8192);

  pre_kernel<<<8, 256, 0, stream>>>(Wf, We, a_fe, a_ef, Wfrag, Wa);
  prep_kernel<<<4864, 256, 0, stream>>>(F0, E0, adj_fe, adj_ef, Wfrag, Wa,
                                        Ftl, Etl, rowF, colEF, colGF,
                                        rowE, colEE, colGE, btfe, btef);
  attn_kernel<<<3072, 256, 0, stream>>>(Ftl, Etl, rowF, colEF, colGF,
                                        rowE, colEE, colGE, btfe, btef, out);
  softmax256_kernel<<<B_ * NF_, 256, 0, stream>>>(out);
}

// Round 17
// 74.250 us; speedup vs baseline: 1.2958x; 1.1948x over previous
//
#include <hip/hip_runtime.h>
#include <hip/hip_bf16.h>
#include <stdint.h>

#define B_  2
#define NF_ 2048
#define NE_ 4096
#define FD_ 128
#define HD_ 64
#define H_  4

#define LOG2E 1.44269504f
#define KH2   4.0f   // per-factor log2 offset; winner products in [2^-12, 2^13] -> f16 normal

typedef unsigned long long u64;
typedef __attribute__((ext_vector_type(4))) float f32x4;
typedef __attribute__((ext_vector_type(8))) short bf16x8;
typedef __attribute__((ext_vector_type(8))) _Float16 f16x8;
typedef __attribute__((ext_vector_type(2))) _Float16 f16x2;
typedef __attribute__((ext_vector_type(4))) unsigned uint32x4;

__device__ __forceinline__ float wave_sum64(float v) {
  #pragma unroll
  for (int m = 32; m >= 1; m >>= 1) v += __shfl_xor(v, m, 64);
  return v;
}
__device__ __forceinline__ float wave_max64(float v) {
  #pragma unroll
  for (int m = 32; m >= 1; m >>= 1) v = fmaxf(v, __shfl_xor(v, m, 64));
  return v;
}
__device__ __forceinline__ unsigned short bf16rne(float x) {
  unsigned u = __float_as_uint(x);
  return (unsigned short)((u + 0x7FFFu + ((u >> 16) & 1u)) >> 16);
}
__device__ __forceinline__ f16x2 u2h2(unsigned u) {
  union { unsigned u; f16x2 h; } c; c.u = u; return c.h;
}
__device__ __forceinline__ unsigned h22u(f16x2 h) {
  union { unsigned u; f16x2 h; } c; c.h = h; return c.u;
}
__device__ __forceinline__ unsigned short f16b(float x) {
  union { _Float16 h; unsigned short s; } c; c.h = (_Float16)x; return c.s;
}

// ---- pre: tile W into A-fragment bf16 layout + Wa = (W @ a) * log2e ----
__global__ __launch_bounds__(256) void pre_kernel(
    const float* __restrict__ Wf, const float* __restrict__ We,
    const float* __restrict__ a_fe, const float* __restrict__ a_ef,
    __hip_bfloat16* __restrict__ Wfrag, float* __restrict__ Wa)
{
  const int lane = threadIdx.x & 63, wid = threadIdx.x >> 6;
  const int dir = blockIdx.x >> 2, h = blockIdx.x & 3;
  const int cl = lane & 15, kq = lane >> 4;
  const float* W = (dir ? We : Wf) + (size_t)h * FD_ * HD_;
  __hip_bfloat16* fb = Wfrag + (size_t)(dir * 4 + h) * 8192;
  #pragma unroll
  for (int db = 0; db < 4; ++db) {
    unsigned short u[8];
    #pragma unroll
    for (int j = 0; j < 8; ++j)
      u[j] = bf16rne(W[(wid * 32 + kq * 8 + j) * HD_ + db * 16 + cl]);
    uint4 pk;
    pk.x = u[0] | ((unsigned)u[1] << 16);
    pk.y = u[2] | ((unsigned)u[3] << 16);
    pk.z = u[4] | ((unsigned)u[5] << 16);
    pk.w = u[6] | ((unsigned)u[7] << 16);
    *(uint4*)(fb + ((size_t)(wid * 4 + db) * 64 + lane) * 8) = pk;
  }
  if (wid == 0) {
    const float* a1 = a_fe + h * HD_;
    const float* a2 = a_ef + h * HD_;
    float* wa = Wa + (size_t)(dir * 4 + h) * 256;
    #pragma unroll
    for (int rep = 0; rep < 2; ++rep) {
      const int f = lane + rep * 64;
      const float* wr = W + (size_t)f * HD_;
      float s1 = 0.f, s2 = 0.f;
      #pragma unroll 8
      for (int d = 0; d < HD_; ++d) {
        s1 = fmaf(wr[d], a1[d], s1);
        s2 = fmaf(wr[d], a2[d], s2);
      }
      wa[f] = s1 * LOG2E;
      wa[128 + f] = s2 * LOG2E;
    }
  }
}

// ---- MFMA proj: 16 rows/wave; fragment-tiled f16 V + f32 row pair + f16 col E/G ----
template<int SWAP, int NN>
__device__ __forceinline__ void proj_mfma(
    const float* __restrict__ X0, const __hip_bfloat16* __restrict__ Wfrag,
    const float* __restrict__ Wa, unsigned short* __restrict__ Vp,
    float2* __restrict__ rowO, unsigned short* __restrict__ colEO,
    unsigned short* __restrict__ colGO, int job, float* __restrict__ ldsX)
{
  const int lane = threadIdx.x & 63;
  const int cl = lane & 15, kq = lane >> 4;
  const int nj = NN >> 4;
  const int nt = job & (nj - 1);
  const int bh = job / nj;
  const int n0 = nt * 16;
  const int h = bh & 3, b = bh >> 2;
  const float* x0 = X0 + ((size_t)b * NN + n0 + cl) * FD_ + kq * 8;
  const __hip_bfloat16* fb = Wfrag + (size_t)((SWAP ? 4 : 0) + h) * 8192;
  const float* wa = Wa + (size_t)((SWAP ? 4 : 0) + h) * 256 + kq * 8;

  bf16x8 wf[4][4];
  #pragma unroll
  for (int ks = 0; ks < 4; ++ks)
    #pragma unroll
    for (int db = 0; db < 4; ++db)
      wf[ks][db] = *(const bf16x8*)(fb + ((size_t)(ks * 4 + db) * 64 + lane) * 8);

  bf16x8 xf[4];
  float d1 = 0.f, d2 = 0.f;
  #pragma unroll
  for (int ks = 0; ks < 4; ++ks) {
    const f32x4 xa = *(const f32x4*)(x0 + ks * 32);
    const f32x4 xb = *(const f32x4*)(x0 + ks * 32 + 4);
    const f32x4 w1a = *(const f32x4*)(wa + ks * 32);
    const f32x4 w1b = *(const f32x4*)(wa + ks * 32 + 4);
    const f32x4 w2a = *(const f32x4*)(wa + 128 + ks * 32);
    const f32x4 w2b = *(const f32x4*)(wa + 128 + ks * 32 + 4);
    #pragma unroll
    for (int i = 0; i < 4; ++i) {
      d1 = fmaf(xa[i], w1a[i], fmaf(xb[i], w1b[i], d1));
      d2 = fmaf(xa[i], w2a[i], fmaf(xb[i], w2b[i], d2));
    }
    #pragma unroll
    for (int i = 0; i < 4; ++i) {
      xf[ks][i]     = (short)bf16rne(xa[i]);
      xf[ks][i + 4] = (short)bf16rne(xb[i]);
    }
  }
  d1 += __shfl_xor(d1, 16, 64); d1 += __shfl_xor(d1, 32, 64);
  d2 += __shfl_xor(d2, 16, 64); d2 += __shfl_xor(d2, 32, 64);

  f32x4 acc[4] = {};
  #pragma unroll
  for (int ks = 0; ks < 4; ++ks)
    #pragma unroll
    for (int db = 0; db < 4; ++db)
      acc[db] = __builtin_amdgcn_mfma_f32_16x16x32_bf16(wf[ks][db], xf[ks],
                                                        acc[db], 0, 0, 0);
  #pragma unroll
  for (int db = 0; db < 4; ++db)
    *(f32x4*)(ldsX + cl * 68 + db * 16 + kq * 4) = acc[db];
  const int mt = n0 >> 6;
  #pragma unroll
  for (int c = 0; c < 2; ++c) {
    const int nb = n0 + c * 8;
    const int ks2 = (nb >> 5) & 1, q2 = (nb >> 3) & 3;
    unsigned short u[8];
    #pragma unroll
    for (int j = 0; j < 8; ++j)
      u[j] = f16b(ldsX[(c * 8 + j) * 68 + lane]);
    uint4 pk;
    pk.x = u[0] | ((unsigned)u[1] << 16);
    pk.y = u[2] | ((unsigned)u[3] << 16);
    pk.z = u[4] | ((unsigned)u[5] << 16);
    pk.w = u[6] | ((unsigned)u[7] << 16);
    *(uint4*)(Vp + ((size_t)((mt * 8 + ks2 * 4 + (lane >> 4)) * 64
                             + q2 * 16 + (lane & 15))) * 8) = pk;
  }
  if (kq == 0) {
    const float rd = SWAP ? d2 : d1;
    const float cd = SWAP ? d1 : d2;
    float2 rp;
    rp.x = exp2f(rd - KH2);
    rp.y = exp2f(0.2f * rd - KH2);
    const size_t idxn = (size_t)bh * NN + n0 + cl;
    rowO[idxn] = rp;
    colEO[idxn] = f16b(exp2f(cd - KH2));
    colGO[idxn] = f16b(exp2f(0.2f * cd - KH2));
  }
}

// ---- bitpack: transposed bits_t[mt][n] ----
__device__ __forceinline__ void bitpack_body(
    const int* __restrict__ adj_fe, const int* __restrict__ adj_ef,
    u64* __restrict__ btfe, u64* __restrict__ btef, int id)
{
  const int lane = threadIdx.x & 63;
  const int* adj; u64* bt; int N, M, mt, g;
  if (id < 8192) {                            // fe: 64 mt x 128 g
    adj = adj_fe; bt = btfe; N = NF_; M = NE_;
    mt = id >> 7; g = id & 127;
  } else {                                    // ef: 32 mt x 256 g
    const int k = id - 8192;
    adj = adj_ef; bt = btef; N = NE_; M = NF_;
    mt = k >> 8; g = k & 255;
  }
  const int* base = adj + (size_t)(g * 16) * M + mt * 64 + lane;
  int v[16];
  #pragma unroll
  for (int r = 0; r < 16; ++r) v[r] = base[(size_t)r * M];
  u64 mine = 0;
  #pragma unroll
  for (int r = 0; r < 16; ++r) {
    u64 msk = __ballot(v[r] != 0);
    if (lane == r) mine = msk;
  }
  if (lane < 16) bt[(size_t)mt * N + g * 16 + lane] = mine;
}

// ---- fused prep ----
__global__ __launch_bounds__(256) void prep_kernel(
    const float* __restrict__ F0, const float* __restrict__ E0,
    const int* __restrict__ adj_fe, const int* __restrict__ adj_ef,
    const __hip_bfloat16* __restrict__ Wfrag, const float* __restrict__ Wa,
    unsigned short* __restrict__ Ftl, unsigned short* __restrict__ Etl,
    float2* __restrict__ rowF, unsigned short* __restrict__ colEF,
    unsigned short* __restrict__ colGF, float2* __restrict__ rowE,
    unsigned short* __restrict__ colEE, unsigned short* __restrict__ colGE,
    u64* __restrict__ btfe, u64* __restrict__ btef)
{
  __shared__ __align__(16) float ldsX[4][16 * 68];
  const int blk = blockIdx.x;
  const int wid = threadIdx.x >> 6;
  if (blk < 4096) {
    bitpack_body(adj_fe, adj_ef, btfe, btef, blk * 4 + wid);
  } else {
    const int job = (blk - 4096) * 4 + wid;   // [0, 3072)
    if (job < 1024) {
      const int bh = job >> 7;
      proj_mfma<0, NF_>(F0, Wfrag, Wa, Ftl + (size_t)bh * 32 * 4096,
                        rowF, colEF, colGF, job, ldsX[wid]);
    } else {
      const int j2 = job - 1024;
      const int bh = j2 >> 8;
      proj_mfma<1, NE_>(E0, Wfrag, Wa, Etl + (size_t)bh * 64 * 4096,
                        rowE, colEE, colGE, j2, ldsX[wid]);
    }
  }
}

// ---- attention inner loop: TWO 16-row fragments share every tile load.
// f16 packed P build (lean live set ~110 regs fits the 3-waves/EU budget —
// unlike R8's bf16 2-frag that spilled at ~200). Col-factor unpack is
// shared by both fragments. 14 loads per 32 rows (vs 13 per 16). ----
template<int TQ, int NN>
__device__ __forceinline__ void attn_wave2(
    const unsigned short* __restrict__ vpp, const unsigned short* __restrict__ colE,
    const unsigned short* __restrict__ colG, const u64* __restrict__ bt,
    float Ea0, float Ga0, float Ea1, float Ga1,
    int n0, int mt0, int cl, int kq,
    f32x4 (&accT0)[4], f32x4 &accS0, f32x4 (&accT1)[4], f32x4 &accS1)
{
  const int lane = threadIdx.x & 63;
  f16x8 ones;
  #pragma unroll
  for (int i = 0; i < 8; ++i) ones[i] = (_Float16)1.0f;

  const unsigned short* tb = vpp + (size_t)mt0 * 4096 + (size_t)lane * 8;
  const unsigned short* cpE = colE + mt0 * 64 + kq * 8;
  const unsigned short* cpG = colG + mt0 * 64 + kq * 8;
  const u64* bp0 = bt + (size_t)mt0 * NN + n0 + cl;
  const u64* bp1 = bp0 + 16;
  const int shk = kq * 8;
  const f16x2 Ea20 = {(_Float16)Ea0, (_Float16)Ea0};
  const f16x2 Ga20 = {(_Float16)Ga0, (_Float16)Ga0};
  const f16x2 Ea21 = {(_Float16)Ea1, (_Float16)Ea1};
  const f16x2 Ga21 = {(_Float16)Ga1, (_Float16)Ga1};

  #pragma unroll 1
  for (int t = 0; t < TQ; ++t) {
    const f16x8 vf0 = *(const f16x8*)(tb);
    const f16x8 vf1 = *(const f16x8*)(tb + 512);
    const f16x8 vf2 = *(const f16x8*)(tb + 1024);
    const f16x8 vf3 = *(const f16x8*)(tb + 1536);
    const f16x8 vf4 = *(const f16x8*)(tb + 2048);
    const f16x8 vf5 = *(const f16x8*)(tb + 2560);
    const f16x8 vf6 = *(const f16x8*)(tb + 3072);
    const f16x8 vf7 = *(const f16x8*)(tb + 3584);
    const uint32x4 ceA = *(const uint32x4*)(cpE);
    const uint32x4 ceB = *(const uint32x4*)(cpE + 32);
    const uint32x4 cgA = *(const uint32x4*)(cpG);
    const uint32x4 cgB = *(const uint32x4*)(cpG + 32);
    const u64 s0 = (*bp0) >> shk;
    const u64 s1 = (*bp1) >> shk;
    tb += 4096; cpE += 64; cpG += 64; bp0 += NN; bp1 += NN;

    uint32x4 pfu0, pfu1;
    unsigned mw0, mw1;

#define PP2(EB, GB, P) {                                                  \
      const f16x2 eb = u2h2((EB)[P]);                                     \
      const f16x2 gb = u2h2((GB)[P]);                                     \
      const f16x2 pm0 = __builtin_elementwise_max(Ea20 * eb, Ga20 * gb);  \
      const f16x2 pm1 = __builtin_elementwise_max(Ea21 * eb, Ga21 * gb);  \
      const int a0 = __builtin_amdgcn_sbfe((int)mw0, 2 * (P), 1);         \
      const int a1 = __builtin_amdgcn_sbfe((int)mw0, 2 * (P) + 1, 1);     \
      const int b0 = __builtin_amdgcn_sbfe((int)mw1, 2 * (P), 1);         \
      const int b1 = __builtin_amdgcn_sbfe((int)mw1, 2 * (P) + 1, 1);     \
      pfu0[P] = h22u(pm0) & (((unsigned)a0 & 0xFFFFu) |                   \
                             ((unsigned)a1 & 0xFFFF0000u));               \
      pfu1[P] = h22u(pm1) & (((unsigned)b0 & 0xFFFFu) |                   \
                             ((unsigned)b1 & 0xFFFF0000u));               \
    }

    // ---- ks = 0 ----
    mw0 = (unsigned)s0; mw1 = (unsigned)s1;
    PP2(ceA, cgA, 0) PP2(ceA, cgA, 1) PP2(ceA, cgA, 2) PP2(ceA, cgA, 3)
    {
      union { uint32x4 u; f16x8 h; } c0, c1; c0.u = pfu0; c1.u = pfu1;
      const f16x8 pf0 = c0.h, pf1 = c1.h;
      accS0 = __builtin_amdgcn_mfma_f32_16x16x32_f16(pf0, ones, accS0, 0, 0, 0);
      accS1 = __builtin_amdgcn_mfma_f32_16x16x32_f16(pf1, ones, accS1, 0, 0, 0);
      accT0[0] = __builtin_amdgcn_mfma_f32_16x16x32_f16(pf0, vf0, accT0[0], 0, 0, 0);
      accT1[0] = __builtin_amdgcn_mfma_f32_16x16x32_f16(pf1, vf0, accT1[0], 0, 0, 0);
      accT0[1] = __builtin_amdgcn_mfma_f32_16x16x32_f16(pf0, vf1, accT0[1], 0, 0, 0);
      accT1[1] = __builtin_amdgcn_mfma_f32_16x16x32_f16(pf1, vf1, accT1[1], 0, 0, 0);
      accT0[2] = __builtin_amdgcn_mfma_f32_16x16x32_f16(pf0, vf2, accT0[2], 0, 0, 0);
      accT1[2] = __builtin_amdgcn_mfma_f32_16x16x32_f16(pf1, vf2, accT1[2], 0, 0, 0);
      accT0[3] = __builtin_amdgcn_mfma_f32_16x16x32_f16(pf0, vf3, accT0[3], 0, 0, 0);
      accT1[3] = __builtin_amdgcn_mfma_f32_16x16x32_f16(pf1, vf3, accT1[3], 0, 0, 0);
    }
    // ---- ks = 1 ----
    mw0 = (unsigned)(s0 >> 32); mw1 = (unsigned)(s1 >> 32);
    PP2(ceB, cgB, 0) PP2(ceB, cgB, 1) PP2(ceB, cgB, 2) PP2(ceB, cgB, 3)
    {
      union { uint32x4 u; f16x8 h; } c0, c1; c0.u = pfu0; c1.u = pfu1;
      const f16x8 pf0 = c0.h, pf1 = c1.h;
      accS0 = __builtin_amdgcn_mfma_f32_16x16x32_f16(pf0, ones, accS0, 0, 0, 0);
      accS1 = __builtin_amdgcn_mfma_f32_16x16x32_f16(pf1, ones, accS1, 0, 0, 0);
      accT0[0] = __builtin_amdgcn_mfma_f32_16x16x32_f16(pf0, vf4, accT0[0], 0, 0, 0);
      accT1[0] = __builtin_amdgcn_mfma_f32_16x16x32_f16(pf1, vf4, accT1[0], 0, 0, 0);
      accT0[1] = __builtin_amdgcn_mfma_f32_16x16x32_f16(pf0, vf5, accT0[1], 0, 0, 0);
      accT1[1] = __builtin_amdgcn_mfma_f32_16x16x32_f16(pf1, vf5, accT1[1], 0, 0, 0);
      accT0[2] = __builtin_amdgcn_mfma_f32_16x16x32_f16(pf0, vf6, accT0[2], 0, 0, 0);
      accT1[2] = __builtin_amdgcn_mfma_f32_16x16x32_f16(pf1, vf6, accT1[2], 0, 0, 0);
      accT0[3] = __builtin_amdgcn_mfma_f32_16x16x32_f16(pf0, vf7, accT0[3], 0, 0, 0);
      accT1[3] = __builtin_amdgcn_mfma_f32_16x16x32_f16(pf1, vf7, accT1[3], 0, 0, 0);
    }
#undef PP2
  }
}

// ---- fused attention: block = 32 rows (2 frags), 4 waves split M.
// amdgpu_waves_per_eu(3,3): ~168-VGPR allocator budget; live set ~110. ----
__global__ __launch_bounds__(256)
__attribute__((amdgpu_waves_per_eu(3, 3)))
void attn_kernel(
    const unsigned short* __restrict__ Ftl, const unsigned short* __restrict__ Etl,
    const float2* __restrict__ rowF, const unsigned short* __restrict__ colEF,
    const unsigned short* __restrict__ colGF, const float2* __restrict__ rowE,
    const unsigned short* __restrict__ colEE, const unsigned short* __restrict__ colGE,
    const u64* __restrict__ btfe, const u64* __restrict__ btef,
    float* __restrict__ out)
{
  __shared__ __align__(16) float ldsO[4 * 4 * 64 * 4];  // 16KB
  __shared__ float ldsS[4 * 16];

  const int lane = threadIdx.x & 63;
  const int wid  = threadIdx.x >> 6;
  const int cl = lane & 15, kq = lane >> 4;
  const int blk = blockIdx.x;

  int N, bh, n0;
  float* obase;
  bool relu;
  f32x4 accT0[4] = {}, accT1[4] = {};
  f32x4 accS0 = {0.f, 0.f, 0.f, 0.f}, accS1 = {0.f, 0.f, 0.f, 0.f};

  if (blk < 512) {             // fe: 8 bh x 64 rowblocks of 32
    bh = blk & 7;
    n0 = (blk >> 3) * 32;
    N = NF_;
    const float2 r0 = rowF[(size_t)bh * NF_ + n0 + cl];
    const float2 r1 = rowF[(size_t)bh * NF_ + n0 + 16 + cl];
    attn_wave2<16, NF_>(Etl + (size_t)bh * 64 * 4096,
                        colEE + (size_t)bh * NE_, colGE + (size_t)bh * NE_,
                        btfe, r0.x, r0.y, r1.x, r1.y,
                        n0, wid * 16, cl, kq, accT0, accS0, accT1, accS1);
    obase = out; relu = false;
  } else {                     // ef: 8 bh x 128 rowblocks of 32
    const int k2 = blk - 512;
    bh = k2 & 7;
    n0 = (k2 >> 3) * 32;
    N = NE_;
    const float2 r0 = rowE[(size_t)bh * NE_ + n0 + cl];
    const float2 r1 = rowE[(size_t)bh * NE_ + n0 + 16 + cl];
    attn_wave2<8, NE_>(Ftl + (size_t)bh * 32 * 4096,
                       colEF + (size_t)bh * NF_, colGF + (size_t)bh * NF_,
                       btef, r0.x, r0.y, r1.x, r1.y,
                       n0, wid * 8, cl, kq, accT0, accS0, accT1, accS1);
    obase = out + (size_t)B_ * NF_ * 256; relu = true;
  }

  const int b = bh >> 2, h = bh & 3;
  // ---- fragment 0 reduction ----
  #pragma unroll
  for (int db = 0; db < 4; ++db)
    *(f32x4*)&ldsO[((db * 4 + wid) * 64 + lane) * 4] = accT0[db];
  if (cl == 0) {
    #pragma unroll
    for (int reg = 0; reg < 4; ++reg)
      ldsS[wid * 16 + kq * 4 + reg] = accS0[reg];
  }
  __syncthreads();
  {
    f32x4 osum = {0.f, 0.f, 0.f, 0.f};
    #pragma unroll
    for (int s = 0; s < 4; ++s)
      osum += *(const f32x4*)&ldsO[((wid * 4 + s) * 64 + lane) * 4];
    float stot[4];
    #pragma unroll
    for (int reg = 0; reg < 4; ++reg) {
      stot[reg] = 0.f;
      #pragma unroll
      for (int s = 0; s < 4; ++s) stot[reg] += ldsS[s * 16 + kq * 4 + reg];
    }
    float* orow = obase + ((size_t)b * N + n0 + kq * 4) * 256 + h * HD_ + wid * 16 + cl;
    #pragma unroll
    for (int reg = 0; reg < 4; ++reg) {
      float v = osum[reg] / stot[reg];
      if (relu) v = fmaxf(v, 0.0f);
      orow[reg * 256] = v;
    }
  }
  __syncthreads();
  // ---- fragment 1 reduction ----
  #pragma unroll
  for (int db = 0; db < 4; ++db)
    *(f32x4*)&ldsO[((db * 4 + wid) * 64 + lane) * 4] = accT1[db];
  if (cl == 0) {
    #pragma unroll
    for (int reg = 0; reg < 4; ++reg)
      ldsS[wid * 16 + kq * 4 + reg] = accS1[reg];
  }
  __syncthreads();
  {
    f32x4 osum = {0.f, 0.f, 0.f, 0.f};
    #pragma unroll
    for (int s = 0; s < 4; ++s)
      osum += *(const f32x4*)&ldsO[((wid * 4 + s) * 64 + lane) * 4];
    float stot[4];
    #pragma unroll
    for (int reg = 0; reg < 4; ++reg) {
      stot[reg] = 0.f;
      #pragma unroll
      for (int s = 0; s < 4; ++s) stot[reg] += ldsS[s * 16 + kq * 4 + reg];
    }
    float* orow = obase + ((size_t)b * N + n0 + 16 + kq * 4) * 256 + h * HD_ + wid * 16 + cl;
    #pragma unroll
    for (int reg = 0; reg < 4; ++reg) {
      float v = osum[reg] / stot[reg];
      if (relu) v = fmaxf(v, 0.0f);
      orow[reg * 256] = v;
    }
  }
}

// in-place softmax over the 256-channel axis
__global__ __launch_bounds__(256) void softmax256_kernel(float* __restrict__ io)
{
  const int t = threadIdx.x;
  const int lane = t & 63, wid = t >> 6;
  float v = io[(long)blockIdx.x * 256 + t];
  __shared__ float red[8];
  float m = wave_max64(v);
  if (lane == 0) red[wid] = m;
  __syncthreads();
  m = fmaxf(fmaxf(red[0], red[1]), fmaxf(red[2], red[3]));
  float e = __expf(v - m);
  float s = wave_sum64(e);
  if (lane == 0) red[4 + wid] = s;
  __syncthreads();
  s = (red[4] + red[5]) + (red[6] + red[7]);
  io[(long)blockIdx.x * 256 + t] = e / s;
}

extern "C" void kernel_launch(void* const* d_in, const int* in_sizes, int n_in,
                              void* d_out, int out_size, void* d_ws, size_t ws_size,
                              hipStream_t stream)
{
  const float* F0   = (const float*)d_in[0];
  const float* E0   = (const float*)d_in[1];
  const int* adj_fe = (const int*)d_in[2];
  const int* adj_ef = (const int*)d_in[3];
  const float* Wf   = (const float*)d_in[4];
  const float* We   = (const float*)d_in[5];
  const float* a_fe = (const float*)d_in[6];
  const float* a_ef = (const float*)d_in[7];
  float* out = (float*)d_out;

  char* ws = (char*)d_ws;
  float2* rowF = (float2*)ws;                               // 128KB
  float2* rowE = (float2*)(ws + (128 << 10));               // 256KB
  unsigned short* colEF = (unsigned short*)(ws + (384 << 10));  // 32KB
  unsigned short* colGF = (unsigned short*)(ws + (416 << 10));  // 32KB
  unsigned short* colEE = (unsigned short*)(ws + (448 << 10));  // 64KB
  unsigned short* colGE = (unsigned short*)(ws + (512 << 10));  // 64KB
  u64* btfe = (u64*)(ws + (576 << 10));                     // 1MB
  u64* btef = btfe + (size_t)NF_ * (NE_ / 64);              // 1MB
  unsigned short* Ftl = (unsigned short*)(btef + (size_t)NE_ * (NF_ / 64)); // 2MB
  unsigned short* Etl = Ftl + (size_t)8 * 32 * 4096;        // 4MB
  __hip_bfloat16* Wfrag = (__hip_bfloat16*)(Etl + (size_t)8 * 64 * 4096);
  float* Wa = (float*)(Wfrag + (size_t)8 * 8192);

  pre_kernel<<<8, 256, 0, stream>>>(Wf, We, a_fe, a_ef, Wfrag, Wa);
  prep_kernel<<<4864, 256, 0, stream>>>(F0, E0, adj_fe, adj_ef, Wfrag, Wa,
                                        Ftl, Etl, rowF, colEF, colGF,
                                        rowE, colEE, colGE, btfe, btef);
  attn_kernel<<<1536, 256, 0, stream>>>(Ftl, Etl, rowF, colEF, colGF,
                                        rowE, colEE, colGE, btfe, btef, out);
  softmax256_kernel<<<B_ * NF_, 256, 0, stream>>>(out);
}